// Round 4
// baseline (410.484 us; speedup 1.0000x reference)
//
#include <hip/hip_runtime.h>
#include <hip/hip_bf16.h>

// ---------------------------------------------------------------------------
// Model_39676907883593: out = dropout(softmax((x1 @ (m @ n^T)) / 64)) @ q
//   B=16, S=2048, D=64, DV=512.  Dropout = JAX threefry, key 42, p_keep=0.75.
// R4: stall-oriented restructure of the fused kernel:
//   - K A-frags straight from global (L1/L2), no K LDS staging phase
//   - Ps double-buffered -> ONE barrier/iter; pipeline QK(it), PV(it-1), TF(it)
//   - Ps stride 136 -> 152 shorts (kills 8-way bank conflict on PV reads)
//   - K hi-only (bf16): error budget ~0.05 vs threshold 0.105
//   - packed bf16 cvt for P; prep: build_k self-stages m (no mT kernel)
// ---------------------------------------------------------------------------

typedef short  s8v __attribute__((ext_vector_type(8)));
typedef float  f4v __attribute__((ext_vector_type(4)));

__device__ __forceinline__ unsigned short f2bf(float f) {
  unsigned int u = __float_as_uint(f);
  u += 0x7fffu + ((u >> 16) & 1u);           // RNE
  return (unsigned short)(u >> 16);
}
__device__ __forceinline__ unsigned int pack_bf2(float a, float b) {
  __hip_bfloat162 h = __float22bfloat162_rn(float2{a, b});
  unsigned int u;
  __builtin_memcpy(&u, &h, 4);
  return u;                                  // a in low 16, b in high 16
}

// rotl via v_alignbit: ({x,x} >> (32-r)) == rotl(x, r)
__device__ __forceinline__ unsigned int rotl(unsigned int x, unsigned int r) {
  return __builtin_amdgcn_alignbit(x, x, 32u - r);
}

// ---- threefry2x32, key = (0, 42); partitionable counter (0, idx) ----------
__device__ __forceinline__ unsigned int jax_bits(unsigned int idx) {
  const unsigned int K0 = 0u, K1 = 42u, K2 = 0x1BD11BDAu ^ K0 ^ K1;
  unsigned int x0 = 0u, x1 = idx;
  x0 += K0; x1 += K1;
#define TF_R(r) { x0 += x1; x1 = rotl(x1, r); x1 ^= x0; }
  TF_R(13) TF_R(15) TF_R(26) TF_R(6)
  x0 += K1; x1 += K2 + 1u;
  TF_R(17) TF_R(29) TF_R(16) TF_R(24)
  x0 += K2; x1 += K0 + 2u;
  TF_R(13) TF_R(15) TF_R(26) TF_R(6)
  x0 += K0; x1 += K1 + 3u;
  TF_R(17) TF_R(29) TF_R(16) TF_R(24)
  x0 += K1; x1 += K2 + 4u;
  TF_R(13) TF_R(15) TF_R(26) TF_R(6)
  x0 += K2; x1 += K0 + 5u;
#undef TF_R
  return x0 ^ x1;
}

__device__ __forceinline__ f4v mfma16(s8v a, s8v b, f4v c) {
  return __builtin_amdgcn_mfma_f32_16x16x32_bf16(a, b, c, 0, 0, 0);
}

// ---------------------------------------------------------------------------
// prep_misc: blockIdx [0,1024) -> x1 cast to bf16 (8 elems/thread, 2.1M)
//            [1024,1280)       -> transpose_q (qT[dv][s] bf16)
// ---------------------------------------------------------------------------
__global__ void prep_misc(const float* __restrict__ x1, const float* __restrict__ q,
                          unsigned short* __restrict__ Xhi,
                          unsigned short* __restrict__ qT) {
  const int blk = blockIdx.x;
  const int t = threadIdx.x;
  if (blk < 1024) {                          // ---- cast x1 -> bf16 ----
    const int i = (blk * 256 + t) * 8;
    float4 a = *(const float4*)&x1[i];
    float4 b = *(const float4*)&x1[i + 4];
    ushort4 o0, o1;
    o0.x = f2bf(a.x); o0.y = f2bf(a.y); o0.z = f2bf(a.z); o0.w = f2bf(a.w);
    o1.x = f2bf(b.x); o1.y = f2bf(b.y); o1.z = f2bf(b.z); o1.w = f2bf(b.w);
    *(ushort4*)&Xhi[i] = o0;
    *(ushort4*)&Xhi[i + 4] = o1;
  } else {                                   // ---- transpose_q ----
    __shared__ unsigned short tile[64][65];
    const int bb = blk - 1024;               // 0..255
    const int s0 = (bb >> 3) * 64;
    const int d0 = (bb & 7) * 64;
#pragma unroll
    for (int k = 0; k < 16; ++k) {
      int lin = t + k * 256;
      int r = lin >> 6, c = lin & 63;
      tile[c][r] = f2bf(q[(size_t)(s0 + r) * 512 + d0 + c]);
    }
    __syncthreads();
#pragma unroll
    for (int k = 0; k < 16; ++k) {
      int lin = t + k * 256;
      int rr = lin >> 6, cc = lin & 63;
      qT[(size_t)(d0 + rr) * 2048 + s0 + cc] = tile[rr][cc];
    }
  }
}

// K[s][d] = bf16( (sum_dv m[d][dv]*n[s][dv]) / 64 ).  128 blocks x 16 rows.
// m chunk [64 d][32 dv] staged transposed in LDS (coalesced global reads).
__global__ __launch_bounds__(256) void build_k(const float* __restrict__ m,
                                               const float* __restrict__ n,
                                               unsigned short* __restrict__ Khi) {
  __shared__ float tile[32][65];             // [dv][d], padded
  const int t = threadIdx.x;
  const int d = t & 63;
  const int w = t >> 6;                      // wave id: rows w*4..w*4+3
  const int s0 = blockIdx.x * 16;
  const int ld_d = t >> 2;                   // 0..63
  const int ld_c = (t & 3) * 8;              // 0,8,16,24
  float a0 = 0.f, a1 = 0.f, a2 = 0.f, a3 = 0.f;
  for (int c0 = 0; c0 < 512; c0 += 32) {
    __syncthreads();                         // prev chunk's reads done
    float4 va = *(const float4*)&m[ld_d * 512 + c0 + ld_c];
    float4 vb = *(const float4*)&m[ld_d * 512 + c0 + ld_c + 4];
    tile[ld_c + 0][ld_d] = va.x; tile[ld_c + 1][ld_d] = va.y;
    tile[ld_c + 2][ld_d] = va.z; tile[ld_c + 3][ld_d] = va.w;
    tile[ld_c + 4][ld_d] = vb.x; tile[ld_c + 5][ld_d] = vb.y;
    tile[ld_c + 6][ld_d] = vb.z; tile[ld_c + 7][ld_d] = vb.w;
    __syncthreads();
    const float* n0 = &n[(size_t)(s0 + w * 4 + 0) * 512 + c0];
    const float* n1 = &n[(size_t)(s0 + w * 4 + 1) * 512 + c0];
    const float* n2 = &n[(size_t)(s0 + w * 4 + 2) * 512 + c0];
    const float* n3 = &n[(size_t)(s0 + w * 4 + 3) * 512 + c0];
#pragma unroll
    for (int j = 0; j < 32; ++j) {
      float mv = tile[j][d];
      a0 = fmaf(mv, n0[j], a0); a1 = fmaf(mv, n1[j], a1);
      a2 = fmaf(mv, n2[j], a2); a3 = fmaf(mv, n3[j], a3);
    }
  }
  Khi[(s0 + w * 4 + 0) * 64 + d] = f2bf(a0 * 0.015625f);
  Khi[(s0 + w * 4 + 1) * 64 + d] = f2bf(a1 * 0.015625f);
  Khi[(s0 + w * 4 + 2) * 64 + d] = f2bf(a2 * 0.015625f);
  Khi[(s0 + w * 4 + 3) * 64 + d] = f2bf(a3 * 0.015625f);
}

// ---------------------------------------------------------------------------
// main fused kernel: 512 blocks (b, rowTile64) x 512 threads (8 waves)
//   per iter (128 keys): QK(it) [K frags from global] -> PV(it-1) [Ps buf^1]
//   -> threefry/exp/pack(it) [writes Ps buf] -> ONE barrier.
// ---------------------------------------------------------------------------
__global__ __launch_bounds__(512, 4) void attn_main(
    const unsigned short* __restrict__ Xhi, const unsigned short* __restrict__ Khi,
    const unsigned short* __restrict__ qT, float* __restrict__ out) {
  __shared__ unsigned short Ps[2][64][152];  // stride 304 B = 16*19: ~2-way banks
  __shared__ float rsum[2][64];

  const int tid  = threadIdx.x;
  const int wave = tid >> 6;
  const int lane = tid & 63;
  const int l15  = lane & 15;
  const int quad = lane >> 4;

  const int b    = blockIdx.x >> 5;          // 16 batches
  const int row0 = (blockIdx.x & 31) * 64;   // 32 row tiles

  const int qk_row = (wave & 3) * 16 + l15;  // local row this lane scores
  const int qk_kg  = (wave >> 2) * 64;       // key-group base within iter

  // X B-frags (bf16), iter-invariant, in registers
  const size_t xg = ((size_t)(b * 2048 + row0 + qk_row)) * 64 + quad * 8;
  const s8v X0 = *(const s8v*)&Xhi[xg];
  const s8v X1 = *(const s8v*)&Xhi[xg + 32];

  f4v acc[4][4];                             // O^T: [mt(dv 16)][nt(row 16)]
#pragma unroll
  for (int mt = 0; mt < 4; ++mt)
#pragma unroll
    for (int nt = 0; nt < 4; ++nt) acc[mt][nt] = f4v{0.f, 0.f, 0.f, 0.f};
  float rs = 0.f;

  const unsigned int idx_row =
      ((unsigned int)(b * 2048 + row0 + qk_row)) * 2048u;

  // ---- phase helpers ----
  auto qk_phase = [&](int it, f4v cf[4]) {
    const int kt = it * 128;
#pragma unroll
    for (int nt = 0; nt < 4; ++nt) {
      const int key = kt + qk_kg + nt * 16 + l15;
      const s8v Ka = *(const s8v*)&Khi[key * 64 + quad * 8];
      const s8v Kb = *(const s8v*)&Khi[key * 64 + 32 + quad * 8];
      f4v c = {0.f, 0.f, 0.f, 0.f};
      c = mfma16(Ka, X0, c);
      cf[nt] = mfma16(Kb, X1, c);
    }
  };
  auto tf_phase = [&](int it, f4v cf[4]) {
    const int kt = it * 128;
    const int buf = it & 1;
#pragma unroll
    for (int nt = 0; nt < 4; ++nt) {
      const unsigned int idx0 =
          idx_row + (unsigned int)(kt + qk_kg + nt * 16 + quad * 4);
      float p[4];
#pragma unroll
      for (int r = 0; r < 4; ++r) {
        float e = __expf(cf[nt][r]);
        rs += e;                             // softmax denom: pre-dropout
        p[r] = (jax_bits(idx0 + r) < 0xC0000000u) ? e : 0.0f;
      }
      *(uint2*)&Ps[buf][(wave & 3) * 16 + l15][qk_kg + nt * 16 + quad * 4] =
          make_uint2(pack_bf2(p[0], p[1]), pack_bf2(p[2], p[3]));
    }
  };
  auto pv_phase = [&](int it) {
    const int kt = it * 128;
    const int buf = it & 1;
#pragma unroll
    for (int ks = 0; ks < 4; ++ks) {
      s8v Va[4];
#pragma unroll
      for (int mt = 0; mt < 4; ++mt)
        Va[mt] = *(const s8v*)&qT[(size_t)(wave * 64 + mt * 16 + l15) * 2048 +
                                  kt + ks * 32 + quad * 8];
#pragma unroll
      for (int nt = 0; nt < 4; ++nt) {
        const s8v Pb = *(const s8v*)&Ps[buf][nt * 16 + l15][ks * 32 + quad * 8];
#pragma unroll
        for (int mt = 0; mt < 4; ++mt)
          acc[mt][nt] = mfma16(Va[mt], Pb, acc[mt][nt]);
      }
    }
  };

  // ---- pipelined loop: one barrier per iter ----
  {
    f4v cf[4];
    qk_phase(0, cf);
    tf_phase(0, cf);
  }
  __syncthreads();
#pragma unroll 2
  for (int it = 1; it < 16; ++it) {
    f4v cf[4];
    qk_phase(it, cf);                        // global K loads prefetchable
    pv_phase(it - 1);                        // MFMA drains under threefry
    tf_phase(it, cf);                        // long VALU block
    __syncthreads();
  }
  pv_phase(15);

  // ---- rowsum: across quads, then across key-groups ----
  {
    float v = rs;
    v += __shfl_xor(v, 16);
    v += __shfl_xor(v, 32);
    if (quad == 0) rsum[wave >> 2][(wave & 3) * 16 + l15] = v;
  }
  __syncthreads();

  // ---- normalize + store ----
#pragma unroll
  for (int nt = 0; nt < 4; ++nt) {
    const int rloc = nt * 16 + l15;
    const int row = row0 + rloc;
    const float inv = 1.0f / (0.75f * (rsum[0][rloc] + rsum[1][rloc]));
    const size_t base = ((size_t)(b * 2048 + row)) * 512 + wave * 64;
#pragma unroll
    for (int mt = 0; mt < 4; ++mt) {
      f4v v = acc[mt][nt];
      v[0] *= inv; v[1] *= inv; v[2] *= inv; v[3] *= inv;
      *(f4v*)&out[base + mt * 16 + quad * 4] = v;
    }
  }
}

// ---------------------------------------------------------------------------
extern "C" void kernel_launch(void* const* d_in, const int* in_sizes, int n_in,
                              void* d_out, int out_size, void* d_ws, size_t ws_size,
                              hipStream_t stream) {
  (void)in_sizes; (void)n_in; (void)out_size; (void)ws_size;
  const float* x1 = (const float*)d_in[0];   // [16][2048][64]
  const float* m  = (const float*)d_in[1];   // [64][512]
  const float* n  = (const float*)d_in[2];   // [2048][512]
  const float* q  = (const float*)d_in[3];   // [2048][512]
  float* out = (float*)d_out;                // [16][2048][512]

  char* ws = (char*)d_ws;
  unsigned short* Khi = (unsigned short*)(ws + 0);         //   262,144 B
  unsigned short* Xhi = (unsigned short*)(ws + 262144);    // 4,194,304 B
  unsigned short* qT  = (unsigned short*)(ws + 4456448);   // 2,097,152 B

  prep_misc<<<1280, 256, 0, stream>>>(x1, q, Xhi, qT);
  build_k<<<128, 256, 0, stream>>>(m, n, Khi);
  attn_main<<<512, 512, 0, stream>>>(Xhi, Khi, qT, out);
}

// Round 5
// 348.251 us; speedup vs baseline: 1.1787x; 1.1787x over previous
//
#include <hip/hip_runtime.h>
#include <hip/hip_bf16.h>

// ---------------------------------------------------------------------------
// Model_39676907883593: out = dropout(softmax((x1 @ (m @ n^T)) / 64)) @ q
//   B=16, S=2048, D=64, DV=512.  Dropout = JAX threefry, key 42, p_keep=0.75.
// R5 = R4 with the spill fixed: phase order QK(it) -> TF(it) -> PV(it-1) so
//   the score frags cf[] are NOT live across PV (R4 peaked >128 VGPRs and
//   spilled: WRITE_SIZE 65->330 MB).  One barrier/iter kept; K from global
//   (L2-resident); Ps double-buffered, stride 152 shorts.
// ---------------------------------------------------------------------------

typedef short  s8v __attribute__((ext_vector_type(8)));
typedef float  f4v __attribute__((ext_vector_type(4)));

__device__ __forceinline__ unsigned short f2bf(float f) {
  unsigned int u = __float_as_uint(f);
  u += 0x7fffu + ((u >> 16) & 1u);           // RNE
  return (unsigned short)(u >> 16);
}
__device__ __forceinline__ unsigned int pack_bf2(float a, float b) {
  __hip_bfloat162 h = __float22bfloat162_rn(float2{a, b});
  unsigned int u;
  __builtin_memcpy(&u, &h, 4);
  return u;                                  // a low 16, b high 16
}

// rotl via v_alignbit: ({x,x} >> (32-r)) == rotl(x, r)
__device__ __forceinline__ unsigned int rotl(unsigned int x, unsigned int r) {
  return __builtin_amdgcn_alignbit(x, x, 32u - r);
}

// ---- threefry2x32, key = (0, 42); partitionable counter (0, idx) ----------
__device__ __forceinline__ unsigned int jax_bits(unsigned int idx) {
  const unsigned int K0 = 0u, K1 = 42u, K2 = 0x1BD11BDAu ^ K0 ^ K1;
  unsigned int x0 = 0u, x1 = idx;
  x0 += K0; x1 += K1;
#define TF_R(r) { x0 += x1; x1 = rotl(x1, r); x1 ^= x0; }
  TF_R(13) TF_R(15) TF_R(26) TF_R(6)
  x0 += K1; x1 += K2 + 1u;
  TF_R(17) TF_R(29) TF_R(16) TF_R(24)
  x0 += K2; x1 += K0 + 2u;
  TF_R(13) TF_R(15) TF_R(26) TF_R(6)
  x0 += K0; x1 += K1 + 3u;
  TF_R(17) TF_R(29) TF_R(16) TF_R(24)
  x0 += K1; x1 += K2 + 4u;
  TF_R(13) TF_R(15) TF_R(26) TF_R(6)
  x0 += K2; x1 += K0 + 5u;
#undef TF_R
  return x0 ^ x1;
}

__device__ __forceinline__ f4v mfma16(s8v a, s8v b, f4v c) {
  return __builtin_amdgcn_mfma_f32_16x16x32_bf16(a, b, c, 0, 0, 0);
}

// ---------------------------------------------------------------------------
// prep_misc: blockIdx [0,1024) -> x1 cast to bf16 (8 elems/thread, 2.1M)
//            [1024,1280)       -> transpose_q (qT[dv][s] bf16)
// ---------------------------------------------------------------------------
__global__ void prep_misc(const float* __restrict__ x1, const float* __restrict__ q,
                          unsigned short* __restrict__ Xhi,
                          unsigned short* __restrict__ qT) {
  const int blk = blockIdx.x;
  const int t = threadIdx.x;
  if (blk < 1024) {                          // ---- cast x1 -> bf16 ----
    const int i = (blk * 256 + t) * 8;
    float4 a = *(const float4*)&x1[i];
    float4 b = *(const float4*)&x1[i + 4];
    ushort4 o0, o1;
    o0.x = f2bf(a.x); o0.y = f2bf(a.y); o0.z = f2bf(a.z); o0.w = f2bf(a.w);
    o1.x = f2bf(b.x); o1.y = f2bf(b.y); o1.z = f2bf(b.z); o1.w = f2bf(b.w);
    *(ushort4*)&Xhi[i] = o0;
    *(ushort4*)&Xhi[i + 4] = o1;
  } else {                                   // ---- transpose_q ----
    __shared__ unsigned short tile[64][65];
    const int bb = blk - 1024;               // 0..255
    const int s0 = (bb >> 3) * 64;
    const int d0 = (bb & 7) * 64;
#pragma unroll
    for (int k = 0; k < 16; ++k) {
      int lin = t + k * 256;
      int r = lin >> 6, c = lin & 63;
      tile[c][r] = f2bf(q[(size_t)(s0 + r) * 512 + d0 + c]);
    }
    __syncthreads();
#pragma unroll
    for (int k = 0; k < 16; ++k) {
      int lin = t + k * 256;
      int rr = lin >> 6, cc = lin & 63;
      qT[(size_t)(d0 + rr) * 2048 + s0 + cc] = tile[rr][cc];
    }
  }
}

// K[s][d] = bf16( (sum_dv m[d][dv]*n[s][dv]) / 64 ).  128 blocks x 16 rows.
__global__ __launch_bounds__(256) void build_k(const float* __restrict__ m,
                                               const float* __restrict__ n,
                                               unsigned short* __restrict__ Khi) {
  __shared__ float tile[32][65];             // [dv][d], padded
  const int t = threadIdx.x;
  const int d = t & 63;
  const int w = t >> 6;                      // wave id: rows w*4..w*4+3
  const int s0 = blockIdx.x * 16;
  const int ld_d = t >> 2;                   // 0..63
  const int ld_c = (t & 3) * 8;              // 0,8,16,24
  float a0 = 0.f, a1 = 0.f, a2 = 0.f, a3 = 0.f;
  for (int c0 = 0; c0 < 512; c0 += 32) {
    __syncthreads();
    float4 va = *(const float4*)&m[ld_d * 512 + c0 + ld_c];
    float4 vb = *(const float4*)&m[ld_d * 512 + c0 + ld_c + 4];
    tile[ld_c + 0][ld_d] = va.x; tile[ld_c + 1][ld_d] = va.y;
    tile[ld_c + 2][ld_d] = va.z; tile[ld_c + 3][ld_d] = va.w;
    tile[ld_c + 4][ld_d] = vb.x; tile[ld_c + 5][ld_d] = vb.y;
    tile[ld_c + 6][ld_d] = vb.z; tile[ld_c + 7][ld_d] = vb.w;
    __syncthreads();
    const float* n0 = &n[(size_t)(s0 + w * 4 + 0) * 512 + c0];
    const float* n1 = &n[(size_t)(s0 + w * 4 + 1) * 512 + c0];
    const float* n2 = &n[(size_t)(s0 + w * 4 + 2) * 512 + c0];
    const float* n3 = &n[(size_t)(s0 + w * 4 + 3) * 512 + c0];
#pragma unroll
    for (int j = 0; j < 32; ++j) {
      float mv = tile[j][d];
      a0 = fmaf(mv, n0[j], a0); a1 = fmaf(mv, n1[j], a1);
      a2 = fmaf(mv, n2[j], a2); a3 = fmaf(mv, n3[j], a3);
    }
  }
  Khi[(s0 + w * 4 + 0) * 64 + d] = f2bf(a0 * 0.015625f);
  Khi[(s0 + w * 4 + 1) * 64 + d] = f2bf(a1 * 0.015625f);
  Khi[(s0 + w * 4 + 2) * 64 + d] = f2bf(a2 * 0.015625f);
  Khi[(s0 + w * 4 + 3) * 64 + d] = f2bf(a3 * 0.015625f);
}

// ---------------------------------------------------------------------------
// main fused kernel: 512 blocks (b, rowTile64) x 512 threads (8 waves)
//   per iter (128 keys): QK(it) [K from global] -> TF(it) [write Ps buf] ->
//   PV(it-1) [read Ps buf^1] -> ONE barrier.  cf[] dies before PV: no spill.
// ---------------------------------------------------------------------------
__global__ __launch_bounds__(512, 4) void attn_main(
    const unsigned short* __restrict__ Xhi, const unsigned short* __restrict__ Khi,
    const unsigned short* __restrict__ qT, float* __restrict__ out) {
  __shared__ unsigned short Ps[2][64][152];  // stride 304 B = 16*19: ~2-way banks
  __shared__ float rsum[2][64];

  const int tid  = threadIdx.x;
  const int wave = tid >> 6;
  const int lane = tid & 63;
  const int l15  = lane & 15;
  const int quad = lane >> 4;

  const int b    = blockIdx.x >> 5;          // 16 batches
  const int row0 = (blockIdx.x & 31) * 64;   // 32 row tiles

  const int qk_row = (wave & 3) * 16 + l15;  // local row this lane scores
  const int qk_kg  = (wave >> 2) * 64;       // key-group base within iter

  // X B-frags (bf16), iter-invariant, in registers
  const size_t xg = ((size_t)(b * 2048 + row0 + qk_row)) * 64 + quad * 8;
  const s8v X0 = *(const s8v*)&Xhi[xg];
  const s8v X1 = *(const s8v*)&Xhi[xg + 32];

  f4v acc[4][4];                             // O^T: [mt(dv 16)][nt(row 16)]
#pragma unroll
  for (int mt = 0; mt < 4; ++mt)
#pragma unroll
    for (int nt = 0; nt < 4; ++nt) acc[mt][nt] = f4v{0.f, 0.f, 0.f, 0.f};
  float rs = 0.f;

  const unsigned int idx_row =
      ((unsigned int)(b * 2048 + row0 + qk_row)) * 2048u;

  // QK(it) + TF(it): produce this iter's probs into Ps[it&1]
  auto qktf_phase = [&](int it) {
    const int kt = it * 128;
    const int buf = it & 1;
    f4v cf[4];
#pragma unroll
    for (int nt = 0; nt < 4; ++nt) {
      const int key = kt + qk_kg + nt * 16 + l15;
      const s8v Ka = *(const s8v*)&Khi[key * 64 + quad * 8];
      const s8v Kb = *(const s8v*)&Khi[key * 64 + 32 + quad * 8];
      f4v c = {0.f, 0.f, 0.f, 0.f};
      c = mfma16(Ka, X0, c);
      cf[nt] = mfma16(Kb, X1, c);
    }
#pragma unroll
    for (int nt = 0; nt < 4; ++nt) {
      const unsigned int idx0 =
          idx_row + (unsigned int)(kt + qk_kg + nt * 16 + quad * 4);
      float p[4];
#pragma unroll
      for (int r = 0; r < 4; ++r) {
        float e = __expf(cf[nt][r]);
        rs += e;                             // softmax denom: pre-dropout
        p[r] = (jax_bits(idx0 + r) < 0xC0000000u) ? e : 0.0f;
      }
      *(uint2*)&Ps[buf][(wave & 3) * 16 + l15][qk_kg + nt * 16 + quad * 4] =
          make_uint2(pack_bf2(p[0], p[1]), pack_bf2(p[2], p[3]));
    }
  };
  // PV(it): consume Ps[it&1]
  auto pv_phase = [&](int it) {
    const int kt = it * 128;
    const int buf = it & 1;
#pragma unroll
    for (int ks = 0; ks < 4; ++ks) {
      s8v Va[4];
#pragma unroll
      for (int mt = 0; mt < 4; ++mt)
        Va[mt] = *(const s8v*)&qT[(size_t)(wave * 64 + mt * 16 + l15) * 2048 +
                                  kt + ks * 32 + quad * 8];
#pragma unroll
      for (int nt = 0; nt < 4; ++nt) {
        const s8v Pb = *(const s8v*)&Ps[buf][nt * 16 + l15][ks * 32 + quad * 8];
#pragma unroll
        for (int mt = 0; mt < 4; ++mt)
          acc[mt][nt] = mfma16(Va[mt], Pb, acc[mt][nt]);
      }
    }
  };

  // ---- pipelined loop: one barrier per iter ----
  qktf_phase(0);
  __syncthreads();
  for (int it = 1; it < 16; ++it) {
    qktf_phase(it);                          // cf live only inside here
    pv_phase(it - 1);
    __syncthreads();
  }
  pv_phase(15);

  // ---- rowsum: across quads, then across key-groups ----
  {
    float v = rs;
    v += __shfl_xor(v, 16);
    v += __shfl_xor(v, 32);
    if (quad == 0) rsum[wave >> 2][(wave & 3) * 16 + l15] = v;
  }
  __syncthreads();

  // ---- normalize + store ----
#pragma unroll
  for (int nt = 0; nt < 4; ++nt) {
    const int rloc = nt * 16 + l15;
    const int row = row0 + rloc;
    const float inv = 1.0f / (0.75f * (rsum[0][rloc] + rsum[1][rloc]));
    const size_t base = ((size_t)(b * 2048 + row)) * 512 + wave * 64;
#pragma unroll
    for (int mt = 0; mt < 4; ++mt) {
      f4v v = acc[mt][nt];
      v[0] *= inv; v[1] *= inv; v[2] *= inv; v[3] *= inv;
      *(f4v*)&out[base + mt * 16 + quad * 4] = v;
    }
  }
}

// ---------------------------------------------------------------------------
extern "C" void kernel_launch(void* const* d_in, const int* in_sizes, int n_in,
                              void* d_out, int out_size, void* d_ws, size_t ws_size,
                              hipStream_t stream) {
  (void)in_sizes; (void)n_in; (void)out_size; (void)ws_size;
  const float* x1 = (const float*)d_in[0];   // [16][2048][64]
  const float* m  = (const float*)d_in[1];   // [64][512]
  const float* n  = (const float*)d_in[2];   // [2048][512]
  const float* q  = (const float*)d_in[3];   // [2048][512]
  float* out = (float*)d_out;                // [16][2048][512]

  char* ws = (char*)d_ws;
  unsigned short* Khi = (unsigned short*)(ws + 0);         //   262,144 B
  unsigned short* Xhi = (unsigned short*)(ws + 262144);    // 4,194,304 B
  unsigned short* qT  = (unsigned short*)(ws + 4456448);   // 2,097,152 B

  prep_misc<<<1280, 256, 0, stream>>>(x1, q, Xhi, qT);
  build_k<<<128, 256, 0, stream>>>(m, n, Khi);
  attn_main<<<512, 512, 0, stream>>>(Xhi, Khi, qT, out);
}